// Round 2
// baseline (182.054 us; speedup 1.0000x reference)
//
#include <hip/hip_runtime.h>
#include <hip/hip_bf16.h>

// Fused GAT value network, one block per batch element. FLOAT32 in/out.
// X (51x32) -> GAT1 (rank-split pairwise scores) -> GAT2 (row 0 only) -> MLP head.
// All intermediates in LDS (~60KB -> 2 blocks/CU, grid 512 = 2/CU exactly).

typedef float f4 __attribute__((ext_vector_type(4)));
typedef const float* cfp;

__device__ __forceinline__ float ldb(cfp p, int i) { return p[i]; }

__device__ __forceinline__ f4 fma4(float s, f4 v, f4 a) {
#pragma unroll
  for (int i = 0; i < 4; ++i) a[i] = fmaf(s, v[i], a[i]);
  return a;
}

#define NN 51
#define HID 64
#define XD 32

__global__ __launch_bounds__(256)
void value_net_kernel(cfp state,
                      cfp wr_w0, cfp wr_b0, cfp wr_w1, cfp wr_b1,
                      cfp wh_w0, cfp wh_b0, cfp wh_w1, cfp wh_b1,
                      cfp g0_w0, cfp g0_b0, cfp g0_w1, cfp g0_b1,
                      cfp g1_w0, cfp g1_b0, cfp g1_w1, cfp g1_b1,
                      cfp v_w0, cfp v_b0, cfp v_w1, cfp v_b1,
                      cfp v_w2, cfp v_b2,
                      float* out)
{
  // 52 rows everywhere: row 51 is read-safe scratch for the register-tiled loops.
  __shared__ f4 sX4[52 * 8];    // X, row-major 32f
  __shared__ f4 sH14[52 * 8];   // H1
  __shared__ f4 sU4[52 * 17];   // U(+b0), stride 68f (17 f4) for bank-quad rotation
  __shared__ f4 sV4[52 * 17];   // V
  __shared__ f4 sWE4[1024];     // staged W0 (4096 f32)  OVERLAID with att matrix (2601f)
  __shared__ f4 sB04[16];       // staged b0
  __shared__ f4 sW14[16];       // staged w1
  __shared__ float sRH[64];     // robot hidden
  __shared__ float sO[32];      // fused row-0 output
  __shared__ float sM1[152];
  __shared__ float sM2[104];

  float* sX  = (float*)sX4;
  float* sH1 = (float*)sH14;
  float* sE  = (float*)sWE4;   // attention scores alias (disjoint live range vs W0)
  float* sWE = (float*)sWE4;
  float* sB0 = (float*)sB04;
  float* sW1 = (float*)sW14;
  float* sHH = (float*)sU4;    // human-hidden scratch (3200f <= 3536f)
  float* sWh = (float*)sV4;    // staged wh_w1 (2048f <= 3536f)
  const f4* sWh4 = (const f4*)sV4;

  const int tid = threadIdx.x;
  const int b = blockIdx.x;
  cfp st = state + b * 750;          // (50,15) slab for this batch

  const float gb0 = g0_b1[0];
  const float gb1 = g1_b1[0];

  // ---- A1: stage GAT0 weights + wh_w1 (f32 in LDS); embedding hidden layers
  {
    const f4* g0w04 = (const f4*)g0_w0;           // 4096 f32 = 1024 f4
    for (int i = tid; i < 1024; i += 256) sWE4[i] = g0w04[i];
    const f4* whw14 = (const f4*)wh_w1;           // 2048 f32 = 512 f4
    f4* sWh4w = (f4*)sV4;
    for (int i = tid; i < 512; i += 256) sWh4w[i] = whw14[i];
  }
  if (tid < HID) {
    sB0[tid] = g0_b0[tid];
    sW1[tid] = g0_w1[tid];
    float a = wr_b0[tid];
#pragma unroll
    for (int k = 0; k < 9; ++k) a = fmaf(st[k], wr_w0[k * HID + tid], a);
    sRH[tid] = fmaxf(a, 0.f);
  }
  if (tid < 32) { sX[NN * XD + tid] = 0.f; sH1[NN * XD + tid] = 0.f; }  // zero scratch rows
  for (int idx = tid; idx < 50 * HID; idx += 256) {
    int i = idx >> 6, t = idx & 63;
    cfp hp = st + i * 15 + 9;
    float a = wh_b0[t];
#pragma unroll
    for (int k = 0; k < 6; ++k) a = fmaf(hp[k], wh_w0[k * HID + t], a);
    sHH[idx] = fmaxf(a, 0.f);
  }
  __syncthreads();

  // ---- A2: embeddings -> sX (row 0 robot, rows 1..50 humans)
  if (tid < XD) {
    float a = wr_b1[tid];
#pragma unroll 8
    for (int t = 0; t < HID; ++t) a = fmaf(sRH[t], wr_w1[t * XD + tid], a);
    sX[tid] = fmaxf(a, 0.f);
  }
  for (int c = tid; c < 50 * 8; c += 256) {
    int i = c >> 3, fg = c & 7;
    f4 a = { wh_b1[fg * 4 + 0], wh_b1[fg * 4 + 1],
             wh_b1[fg * 4 + 2], wh_b1[fg * 4 + 3] };
    const f4* hh4 = (const f4*)(sHH + i * HID);
#pragma unroll
    for (int tg = 0; tg < 16; ++tg) {
      f4 h = hh4[tg];
#pragma unroll
      for (int e = 0; e < 4; ++e) a = fma4(h[e], sWh4[(tg * 4 + e) * 8 + fg], a);
    }
#pragma unroll
    for (int e = 0; e < 4; ++e) a[e] = fmaxf(a[e], 0.f);
    sX4[(1 + i) * 8 + fg] = a;
  }
  __syncthreads();

  // ---- B: U = X@W0[0:32,:] + b0 ; V = X@W0[32:64,:]   (2-row blocking shares W0 reads)
  for (int c = tid; c < 26 * 16; c += 256) {
    int ip = c >> 4, tg = c & 15;
    int i0 = ip, i1 = ip + 26;               // i1 may be 51 (scratch row, safe)
    f4 au0 = {0,0,0,0}, av0 = {0,0,0,0}, au1 = {0,0,0,0}, av1 = {0,0,0,0};
#pragma unroll
    for (int kg = 0; kg < 8; ++kg) {
      f4 x0 = sX4[i0 * 8 + kg];
      f4 x1 = sX4[i1 * 8 + kg];
#pragma unroll
      for (int e = 0; e < 4; ++e) {
        int k = kg * 4 + e;
        f4 wU = sWE4[k * 16 + tg];
        f4 wV = sWE4[(k + 32) * 16 + tg];
        au0 = fma4(x0[e], wU, au0);
        av0 = fma4(x0[e], wV, av0);
        au1 = fma4(x1[e], wU, au1);
        av1 = fma4(x1[e], wV, av1);
      }
    }
    f4 b0v = sB04[tg];
    sU4[i0 * 17 + tg] = au0 + b0v;
    sV4[i0 * 17 + tg] = av0;
    sU4[i1 * 17 + tg] = au1 + b0v;
    sV4[i1 * 17 + tg] = av1;
  }
  __syncthreads();

  // ---- C: pairwise scores, 4x2 register tile. e(i,j) = leaky(w1 . relu(U_i + V_j) + b1)
  for (int T = tid; T < 13 * 26; T += 256) {
    int it = T / 26;
    int jt = T - it * 26;
    const f4* Ua = sU4 + it * 17;
    const f4* Ub = sU4 + (it + 13) * 17;
    const f4* Uc = sU4 + (it + 26) * 17;
    const f4* Ud = sU4 + (it + 39) * 17;
    const f4* Va = sV4 + jt * 17;
    const f4* Vb = sV4 + (jt + 26) * 17;
    float a00 = 0, a01 = 0, a10 = 0, a11 = 0, a20 = 0, a21 = 0, a30 = 0, a31 = 0;
#pragma unroll
    for (int g = 0; g < 16; ++g) {
      f4 u0 = Ua[g], u1 = Ub[g], u2 = Uc[g], u3 = Ud[g];
      f4 v0 = Va[g], v1 = Vb[g];
      f4 w = sW14[g];
#pragma unroll
      for (int e = 0; e < 4; ++e) {
        float we = w[e];
        float p;
        p = fmaxf(u0[e] + v0[e], 0.f); a00 = fmaf(p, we, a00);
        p = fmaxf(u0[e] + v1[e], 0.f); a01 = fmaf(p, we, a01);
        p = fmaxf(u1[e] + v0[e], 0.f); a10 = fmaf(p, we, a10);
        p = fmaxf(u1[e] + v1[e], 0.f); a11 = fmaf(p, we, a11);
        p = fmaxf(u2[e] + v0[e], 0.f); a20 = fmaf(p, we, a20);
        p = fmaxf(u2[e] + v1[e], 0.f); a21 = fmaf(p, we, a21);
        p = fmaxf(u3[e] + v0[e], 0.f); a30 = fmaf(p, we, a30);
        p = fmaxf(u3[e] + v1[e], 0.f); a31 = fmaf(p, we, a31);
      }
    }
    float accs[8] = {a00, a01, a10, a11, a20, a21, a30, a31};
#pragma unroll
    for (int r = 0; r < 4; ++r)
#pragma unroll
      for (int cc = 0; cc < 2; ++cc) {
        int i = it + 13 * r, j = jt + 26 * cc;
        if (i < NN && j < NN) {
          float A = accs[r * 2 + cc] + gb0;
          float e = A > 0.f ? A : 0.04f * A;
          sE[i * NN + j] = (j == 0 && i > 0) ? -1e30f : e;  // adj mask: rows>=1 drop col 0
        }
      }
  }
  __syncthreads();

  // ---- D: row softmax (thread per row)
  if (tid < NN) {
    float* row = sE + tid * NN;
    const int j0 = (tid == 0) ? 0 : 1;
    float m = -3.0e38f;
    for (int j = j0; j < NN; ++j) m = fmaxf(m, row[j]);
    float s = 0.f;
    for (int j = j0; j < NN; ++j) { float v = __expf(row[j] - m); row[j] = v; s += v; }
    float inv = 1.f / s;
    for (int j = j0; j < NN; ++j) row[j] *= inv;
    if (tid > 0) row[0] = 0.f;   // masked entry contributes 0 in the matvec
  }
  __syncthreads();

  // ---- E: H1 = att @ X
  for (int c = tid; c < NN * 4; c += 256) {
    int i = c >> 2, q = c & 3;
    f4 a0 = {0,0,0,0}, a1 = {0,0,0,0};
    const float* arow = sE + i * NN;
#pragma unroll 3
    for (int j = 0; j < NN; ++j) {
      float att = arow[j];
      a0 = fma4(att, sX4[j * 8 + q * 2], a0);
      a1 = fma4(att, sX4[j * 8 + q * 2 + 1], a1);
    }
    sH14[i * 8 + q * 2] = a0;
    sH14[i * 8 + q * 2 + 1] = a1;
  }
  __syncthreads();

  // ---- F1: restage layer-1 GAT weights (overwrites att matrix — consumed)
  {
    const f4* g1w04 = (const f4*)g1_w0;
    for (int i = tid; i < 1024; i += 256) sWE4[i] = g1w04[i];
  }
  if (tid < HID) { sB0[tid] = g1_b0[tid]; sW1[tid] = g1_w1[tid]; }
  __syncthreads();

  // ---- F2: V2 = H1@W0b (all rows); U2 = H1[0]@W0a + b0 (row 0 only — only row 0 of
  //          the GAT2 output is consumed downstream)
  for (int c = tid; c < 26 * 16; c += 256) {
    int jp = c >> 4, tg = c & 15;
    int j0 = jp, j1 = jp + 26;
    f4 av0 = {0,0,0,0}, av1 = {0,0,0,0};
#pragma unroll
    for (int kg = 0; kg < 8; ++kg) {
      f4 h0 = sH14[j0 * 8 + kg];
      f4 h1 = sH14[j1 * 8 + kg];
#pragma unroll
      for (int e = 0; e < 4; ++e) {
        f4 wV = sWE4[(kg * 4 + e + 32) * 16 + tg];
        av0 = fma4(h0[e], wV, av0);
        av1 = fma4(h1[e], wV, av1);
      }
    }
    sV4[j0 * 17 + tg] = av0;
    sV4[j1 * 17 + tg] = av1;
  }
  if (tid < 16) {
    f4 au = {0,0,0,0};
#pragma unroll
    for (int kg = 0; kg < 8; ++kg) {
      f4 h = sH14[kg];
#pragma unroll
      for (int e = 0; e < 4; ++e) au = fma4(h[e], sWE4[(kg * 4 + e) * 16 + tid], au);
    }
    sU4[tid] = au + sB04[tid];
  }
  __syncthreads();

  // ---- G: GAT2 row-0 scores + softmax (wave 0), att -> sE[0..50]
  if (tid < 64) {
    int j = tid;
    float e = -3.0e38f;
    if (j < NN) {
      float acc = gb1;
#pragma unroll
      for (int g = 0; g < 16; ++g) {
        f4 u = sU4[g];
        f4 v = sV4[j * 17 + g];
        f4 w = sW14[g];
#pragma unroll
        for (int x = 0; x < 4; ++x) acc = fmaf(fmaxf(u[x] + v[x], 0.f), w[x], acc);
      }
      e = acc > 0.f ? acc : 0.04f * acc;
    }
    float m = e;
#pragma unroll
    for (int o = 32; o; o >>= 1) m = fmaxf(m, __shfl_xor(m, o, 64));
    float p = (j < NN) ? __expf(e - m) : 0.f;
    float s = p;
#pragma unroll
    for (int o = 32; o; o >>= 1) s += __shfl_xor(s, o, 64);
    if (j < NN) sE[j] = p / s;
  }
  __syncthreads();

  // ---- H: row 0 of (H1 + H2 + X)
  if (tid < XD) {
    float a = 0.f;
    for (int j = 0; j < NN; ++j) a = fmaf(sE[j], sH1[j * XD + tid], a);
    sO[tid] = a + sH1[tid] + sX[tid];
  }
  __syncthreads();

  // ---- I: value head 32 -> 150 -> 100 -> 1 (relu at each layer)
  if (tid < 150) {
    float a = v_b0[tid];
#pragma unroll 8
    for (int f = 0; f < XD; ++f) a = fmaf(sO[f], v_w0[f * 150 + tid], a);
    sM1[tid] = fmaxf(a, 0.f);
  }
  __syncthreads();
  if (tid < 100) {
    float a = v_b1[tid];
#pragma unroll 10
    for (int t = 0; t < 150; ++t) a = fmaf(sM1[t], v_w1[t * 100 + tid], a);
    sM2[tid] = fmaxf(a, 0.f);
  }
  __syncthreads();
  if (tid < 64) {
    float a = sM2[tid] * v_w2[tid];
    if (tid < 36) a = fmaf(sM2[tid + 64], v_w2[tid + 64], a);
#pragma unroll
    for (int o = 32; o; o >>= 1) a += __shfl_xor(a, o, 64);
    if (tid == 0) out[b] = fmaxf(a + v_b2[0], 0.f);
  }
}

extern "C" void kernel_launch(void* const* d_in, const int* in_sizes, int n_in,
                              void* d_out, int out_size, void* d_ws, size_t ws_size,
                              hipStream_t stream) {
  cfp state = (cfp)d_in[0];
  // d_in[1] = dropout (int scalar, 0) — unused
  cfp wr_w0 = (cfp)d_in[2],  wr_b0 = (cfp)d_in[3];
  cfp wr_w1 = (cfp)d_in[4],  wr_b1 = (cfp)d_in[5];
  cfp wh_w0 = (cfp)d_in[6],  wh_b0 = (cfp)d_in[7];
  cfp wh_w1 = (cfp)d_in[8],  wh_b1 = (cfp)d_in[9];
  cfp g0_w0 = (cfp)d_in[10], g0_b0 = (cfp)d_in[11];
  cfp g0_w1 = (cfp)d_in[12], g0_b1 = (cfp)d_in[13];
  cfp g1_w0 = (cfp)d_in[14], g1_b0 = (cfp)d_in[15];
  cfp g1_w1 = (cfp)d_in[16], g1_b1 = (cfp)d_in[17];
  cfp v_w0  = (cfp)d_in[18], v_b0  = (cfp)d_in[19];
  cfp v_w1  = (cfp)d_in[20], v_b1  = (cfp)d_in[21];
  cfp v_w2  = (cfp)d_in[22], v_b2  = (cfp)d_in[23];
  float* out = (float*)d_out;

  const int B = in_sizes[0] / 750;   // (B, 50, 15)
  hipLaunchKernelGGL(value_net_kernel, dim3(B), dim3(256), 0, stream,
                     state,
                     wr_w0, wr_b0, wr_w1, wr_b1,
                     wh_w0, wh_b0, wh_w1, wh_b1,
                     g0_w0, g0_b0, g0_w1, g0_b1,
                     g1_w0, g1_b0, g1_w1, g1_b1,
                     v_w0, v_b0, v_w1, v_b1, v_w2, v_b2,
                     out);
}

// Round 3
// 142.498 us; speedup vs baseline: 1.2776x; 1.2776x over previous
//
#include <hip/hip_runtime.h>
#include <hip/hip_bf16.h>

// Fused GAT value network, one block per batch element. FLOAT32 in/out.
// Rank-split GAT1 scores, row-0-only GAT2, all intermediates in LDS.
// R3: bigger register tiles (fewer ds_read_b128 per FMA), wave-parallel
// softmax, k-split parallel value head, padded strides for bank conflicts.

typedef float f4 __attribute__((ext_vector_type(4)));
typedef const float* cfp;

__device__ __forceinline__ f4 fma4(float s, f4 v, f4 a) {
#pragma unroll
  for (int i = 0; i < 4; ++i) a[i] = fmaf(s, v[i], a[i]);
  return a;
}

#define NN 51
#define HID 64
#define XD 32
#define XS 9   // row stride of X/H1 in f4 (36 floats) — breaks 4-way bank conflicts

__global__ __launch_bounds__(256)
void value_net_kernel(cfp state,
                      cfp wr_w0, cfp wr_b0, cfp wr_w1, cfp wr_b1,
                      cfp wh_w0, cfp wh_b0, cfp wh_w1, cfp wh_b1,
                      cfp g0_w0, cfp g0_b0, cfp g0_w1, cfp g0_b1,
                      cfp g1_w0, cfp g1_b0, cfp g1_w1, cfp g1_b1,
                      cfp v_w0, cfp v_b0, cfp v_w1, cfp v_b1,
                      cfp v_w2, cfp v_b2,
                      float* out)
{
  // Row 51 everywhere is read-safe scratch for the register-tiled loops.
  __shared__ f4 sX4[52 * XS];   // X
  __shared__ f4 sH14[52 * XS];  // H1
  __shared__ f4 sU4[52 * 17];   // U(+b0), stride 68f   (also sHH scratch, stride 68)
  __shared__ f4 sV4[52 * 17];   // V                    (also staged wh_w1)
  __shared__ f4 sWE4[1024];     // staged W0 (4096 f)   (also att matrix + head partials)
  __shared__ f4 sB04[16];
  __shared__ f4 sW14[16];
  __shared__ float sRH[64];
  __shared__ float sO[32];
  __shared__ float sM1[152];
  __shared__ float sM2[104];

  float* sX  = (float*)sX4;
  float* sH1 = (float*)sH14;
  float* sE  = (float*)sWE4;   // att scores alias (disjoint live range vs W0)
  float* sWE = (float*)sWE4;
  float* sB0 = (float*)sB04;
  float* sW1 = (float*)sW14;
  float* sHH = (float*)sU4;    // human-hidden scratch, row stride 68
  const f4* sWh4 = (const f4*)sV4;

  const int tid = threadIdx.x;
  const int b = blockIdx.x;
  cfp st = state + b * 750;

  const float gb0 = g0_b1[0];
  const float gb1 = g1_b1[0];

  // ---- A1: stage weights; robot/human hidden layers
  {
    const f4* g0w04 = (const f4*)g0_w0;
    for (int i = tid; i < 1024; i += 256) sWE4[i] = g0w04[i];
    const f4* whw14 = (const f4*)wh_w1;
    f4* sWh4w = (f4*)sV4;
    for (int i = tid; i < 512; i += 256) sWh4w[i] = whw14[i];
  }
  if (tid < HID) {
    sB0[tid] = g0_b0[tid];
    sW1[tid] = g0_w1[tid];
    float a = wr_b0[tid];
#pragma unroll
    for (int k = 0; k < 9; ++k) a = fmaf(st[k], wr_w0[k * HID + tid], a);
    sRH[tid] = fmaxf(a, 0.f);
  }
  if (tid < XS) { sX4[51 * XS + tid] = (f4){0,0,0,0}; sH14[51 * XS + tid] = (f4){0,0,0,0}; }
  for (int idx = tid; idx < 50 * HID; idx += 256) {
    int i = idx >> 6, t = idx & 63;
    cfp hp = st + i * 15 + 9;
    float a = wh_b0[t];
#pragma unroll
    for (int k = 0; k < 6; ++k) a = fmaf(hp[k], wh_w0[k * HID + t], a);
    sHH[i * 68 + t] = fmaxf(a, 0.f);
  }
  __syncthreads();

  // ---- A2: embeddings -> sX (row 0 robot, rows 1..50 humans), 2-row tile
  if (tid < XD) {
    float a = wr_b1[tid];
#pragma unroll 8
    for (int t = 0; t < HID; ++t) a = fmaf(sRH[t], wr_w1[t * XD + tid], a);
    sX[tid] = fmaxf(a, 0.f);
  }
  if (tid < 200) {
    int ip = tid >> 3, fg = tid & 7;           // rows ip, ip+25
    f4 a0 = { wh_b1[fg * 4 + 0], wh_b1[fg * 4 + 1],
              wh_b1[fg * 4 + 2], wh_b1[fg * 4 + 3] };
    f4 a1 = a0;
    const f4* h0 = sU4 + ip * 17;
    const f4* h1 = sU4 + (ip + 25) * 17;
#pragma unroll 4
    for (int tg = 0; tg < 16; ++tg) {
      f4 ha = h0[tg], hb = h1[tg];
#pragma unroll
      for (int e = 0; e < 4; ++e) {
        f4 w = sWh4[(tg * 4 + e) * 8 + fg];
        a0 = fma4(ha[e], w, a0);
        a1 = fma4(hb[e], w, a1);
      }
    }
#pragma unroll
    for (int e = 0; e < 4; ++e) { a0[e] = fmaxf(a0[e], 0.f); a1[e] = fmaxf(a1[e], 0.f); }
    sX4[(1 + ip) * XS + fg] = a0;
    sX4[(26 + ip) * XS + fg] = a1;
  }
  __syncthreads();

  // ---- B: U = X@W0a + b0 ; V = X@W0b  — 4-row tile, 208 tasks
  if (tid < 208) {
    int ip = tid >> 4, tg = tid & 15;          // rows ip+13r (max 12+39=51 scratch)
    f4 au[4] = {{0,0,0,0},{0,0,0,0},{0,0,0,0},{0,0,0,0}};
    f4 av[4] = {{0,0,0,0},{0,0,0,0},{0,0,0,0},{0,0,0,0}};
#pragma unroll 2
    for (int kg = 0; kg < 8; ++kg) {
      f4 x0 = sX4[ip * XS + kg];
      f4 x1 = sX4[(ip + 13) * XS + kg];
      f4 x2 = sX4[(ip + 26) * XS + kg];
      f4 x3 = sX4[(ip + 39) * XS + kg];
#pragma unroll
      for (int e = 0; e < 4; ++e) {
        int k = kg * 4 + e;
        f4 wU = sWE4[k * 16 + tg];
        f4 wV = sWE4[(k + 32) * 16 + tg];
        au[0] = fma4(x0[e], wU, au[0]); av[0] = fma4(x0[e], wV, av[0]);
        au[1] = fma4(x1[e], wU, au[1]); av[1] = fma4(x1[e], wV, av[1]);
        au[2] = fma4(x2[e], wU, au[2]); av[2] = fma4(x2[e], wV, av[2]);
        au[3] = fma4(x3[e], wU, au[3]); av[3] = fma4(x3[e], wV, av[3]);
      }
    }
    f4 b0v = sB04[tg];
#pragma unroll
    for (int r = 0; r < 4; ++r) {
      int row = ip + 13 * r;
      sU4[row * 17 + tg] = au[r] + b0v;
      sV4[row * 17 + tg] = av[r];
    }
  }
  __syncthreads();

  // ---- C: pairwise scores, 4x4 register tile (169 tasks, single round)
  if (tid < 169) {
    int it = tid / 13, jt = tid - (tid / 13) * 13;
    const f4* U0 = sU4 + it * 17;
    const f4* V0 = sV4 + jt * 17;
    float acc[4][4] = {};
#pragma unroll 4
    for (int g = 0; g < 16; ++g) {
      f4 u0 = U0[g], u1 = U0[13 * 17 + g], u2 = U0[26 * 17 + g], u3 = U0[39 * 17 + g];
      f4 v0 = V0[g], v1 = V0[13 * 17 + g], v2 = V0[26 * 17 + g], v3 = V0[39 * 17 + g];
      f4 w = sW14[g];
#pragma unroll
      for (int e = 0; e < 4; ++e) {
        float we = w[e];
        float uu[4] = {u0[e], u1[e], u2[e], u3[e]};
        float vv[4] = {v0[e], v1[e], v2[e], v3[e]};
#pragma unroll
        for (int r = 0; r < 4; ++r)
#pragma unroll
          for (int cc = 0; cc < 4; ++cc)
            acc[r][cc] = fmaf(fmaxf(uu[r] + vv[cc], 0.f), we, acc[r][cc]);
      }
    }
#pragma unroll
    for (int r = 0; r < 4; ++r) {
      int i = it + 13 * r;
      if (i < NN) {
#pragma unroll
        for (int cc = 0; cc < 4; ++cc) {
          int j = jt + 13 * cc;
          if (j < NN) {
            float A = acc[r][cc] + gb0;
            float e = A > 0.f ? A : 0.04f * A;
            sE[i * NN + j] = (j == 0 && i > 0) ? -1e30f : e;
          }
        }
      }
    }
  }
  __syncthreads();

  // ---- D: row softmax — lane-parallel rows across all 4 waves
  {
    int lane = tid & 63, w = tid >> 6;
    for (int r = w; r < NN; r += 4) {
      float* row = sE + r * NN;
      float e = (lane < NN) ? row[lane] : -3.0e38f;
      float m = e;
#pragma unroll
      for (int o = 32; o; o >>= 1) m = fmaxf(m, __shfl_xor(m, o, 64));
      float p = (lane < NN) ? __expf(e - m) : 0.f;
      float s = p;
#pragma unroll
      for (int o = 32; o; o >>= 1) s += __shfl_xor(s, o, 64);
      if (lane < NN) row[lane] = p / s;  // col0 (r>0): exp(-1e30-m)=0 -> stays 0
    }
  }
  __syncthreads();

  // ---- E: H1 = att @ X  — 2-row tile (104 tasks)
  if (tid < 104) {
    int ip = tid >> 2, q = tid & 3;            // rows ip, ip+26 (51 = finite scratch)
    const float* a0r = sE + ip * NN;
    const float* a1r = sE + (ip + 26) * NN;
    f4 b00 = {0,0,0,0}, b01 = {0,0,0,0}, b10 = {0,0,0,0}, b11 = {0,0,0,0};
#pragma unroll 3
    for (int j = 0; j < NN; ++j) {
      float t0 = a0r[j], t1 = a1r[j];
      f4 x0 = sX4[j * XS + q * 2], x1 = sX4[j * XS + q * 2 + 1];
      b00 = fma4(t0, x0, b00); b01 = fma4(t0, x1, b01);
      b10 = fma4(t1, x0, b10); b11 = fma4(t1, x1, b11);
    }
    sH14[ip * XS + q * 2] = b00;       sH14[ip * XS + q * 2 + 1] = b01;
    sH14[(ip + 26) * XS + q * 2] = b10; sH14[(ip + 26) * XS + q * 2 + 1] = b11;
  }
  __syncthreads();

  // ---- F1: restage layer-1 GAT weights (att matrix consumed)
  {
    const f4* g1w04 = (const f4*)g1_w0;
    for (int i = tid; i < 1024; i += 256) sWE4[i] = g1w04[i];
  }
  if (tid < HID) { sB0[tid] = g1_b0[tid]; sW1[tid] = g1_w1[tid]; }
  __syncthreads();

  // ---- F2: V2 = H1@W0b (all rows, 4-row tile); U2 = H1[0]@W0a + b0 (row 0 only)
  if (tid < 208) {
    int jp = tid >> 4, tg = tid & 15;
    f4 av[4] = {{0,0,0,0},{0,0,0,0},{0,0,0,0},{0,0,0,0}};
#pragma unroll 2
    for (int kg = 0; kg < 8; ++kg) {
      f4 h0 = sH14[jp * XS + kg];
      f4 h1 = sH14[(jp + 13) * XS + kg];
      f4 h2 = sH14[(jp + 26) * XS + kg];
      f4 h3 = sH14[(jp + 39) * XS + kg];
#pragma unroll
      for (int e = 0; e < 4; ++e) {
        f4 wV = sWE4[(kg * 4 + e + 32) * 16 + tg];
        av[0] = fma4(h0[e], wV, av[0]);
        av[1] = fma4(h1[e], wV, av[1]);
        av[2] = fma4(h2[e], wV, av[2]);
        av[3] = fma4(h3[e], wV, av[3]);
      }
    }
#pragma unroll
    for (int r = 0; r < 4; ++r) sV4[(jp + 13 * r) * 17 + tg] = av[r];
  }
  if (tid >= 208 && tid < 224) {
    int tg = tid - 208;
    f4 au = {0,0,0,0};
#pragma unroll
    for (int kg = 0; kg < 8; ++kg) {
      f4 h = sH14[kg];
#pragma unroll
      for (int e = 0; e < 4; ++e) au = fma4(h[e], sWE4[(kg * 4 + e) * 16 + tg], au);
    }
    sU4[tg] = au + sB04[tg];
  }
  __syncthreads();

  // ---- G: GAT2 row-0 scores + softmax (wave 0) -> sE[0..50]
  if (tid < 64) {
    int j = tid;
    float e = -3.0e38f;
    if (j < NN) {
      float acc = gb1;
#pragma unroll 4
      for (int g = 0; g < 16; ++g) {
        f4 u = sU4[g];
        f4 v = sV4[j * 17 + g];
        f4 w = sW14[g];
#pragma unroll
        for (int x = 0; x < 4; ++x) acc = fmaf(fmaxf(u[x] + v[x], 0.f), w[x], acc);
      }
      e = acc > 0.f ? acc : 0.04f * acc;
    }
    float m = e;
#pragma unroll
    for (int o = 32; o; o >>= 1) m = fmaxf(m, __shfl_xor(m, o, 64));
    float p = (j < NN) ? __expf(e - m) : 0.f;
    float s = p;
#pragma unroll
    for (int o = 32; o; o >>= 1) s += __shfl_xor(s, o, 64);
    if (j < NN) sE[j] = p / s;
  }
  __syncthreads();

  // ---- H: row 0 of (H1 + H2 + X)
  if (tid < XD) {
    float a = 0.f;
    for (int j = 0; j < NN; ++j) a = fmaf(sE[j], sH1[j * 36 + tid], a);
    sO[tid] = a + sH1[tid] + sX[tid];
  }
  __syncthreads();

  // ---- I: value head 32 -> 150 -> 100 -> 1, k-split + float2-coalesced
  if (tid < 225) {
    int kp = tid / 75, t2 = tid % 75;
    int k0 = kp * 11, k1 = (k0 + 11 < 32) ? k0 + 11 : 32;
    const float2* w = (const float2*)v_w0;
    float2 acc = {0.f, 0.f};
    for (int k = k0; k < k1; ++k) {
      float2 ww = w[k * 75 + t2];
      float xv = sO[k];
      acc.x = fmaf(xv, ww.x, acc.x);
      acc.y = fmaf(xv, ww.y, acc.y);
    }
    ((float2*)(sE + 256 + kp * 152))[t2] = acc;
  }
  __syncthreads();
  if (tid < 150) {
    float a = v_b0[tid] + sE[256 + tid] + sE[256 + 152 + tid] + sE[256 + 304 + tid];
    sM1[tid] = fmaxf(a, 0.f);
  }
  __syncthreads();
  if (tid < 250) {
    int kp = tid / 50, t2 = tid % 50;
    int k0 = kp * 30;
    const float2* w = (const float2*)v_w1;
    float2 acc = {0.f, 0.f};
    for (int k = k0; k < k0 + 30; ++k) {
      float2 ww = w[k * 50 + t2];
      float xv = sM1[k];
      acc.x = fmaf(xv, ww.x, acc.x);
      acc.y = fmaf(xv, ww.y, acc.y);
    }
    ((float2*)(sE + 768 + kp * 100))[t2] = acc;
  }
  __syncthreads();
  if (tid < 100) {
    float a = v_b1[tid];
#pragma unroll
    for (int kp = 0; kp < 5; ++kp) a += sE[768 + kp * 100 + tid];
    sM2[tid] = fmaxf(a, 0.f);
  }
  __syncthreads();
  if (tid < 64) {
    float a = sM2[tid] * v_w2[tid];
    if (tid < 36) a = fmaf(sM2[tid + 64], v_w2[tid + 64], a);
#pragma unroll
    for (int o = 32; o; o >>= 1) a += __shfl_xor(a, o, 64);
    if (tid == 0) out[b] = fmaxf(a + v_b2[0], 0.f);
  }
}

extern "C" void kernel_launch(void* const* d_in, const int* in_sizes, int n_in,
                              void* d_out, int out_size, void* d_ws, size_t ws_size,
                              hipStream_t stream) {
  cfp state = (cfp)d_in[0];
  cfp wr_w0 = (cfp)d_in[2],  wr_b0 = (cfp)d_in[3];
  cfp wr_w1 = (cfp)d_in[4],  wr_b1 = (cfp)d_in[5];
  cfp wh_w0 = (cfp)d_in[6],  wh_b0 = (cfp)d_in[7];
  cfp wh_w1 = (cfp)d_in[8],  wh_b1 = (cfp)d_in[9];
  cfp g0_w0 = (cfp)d_in[10], g0_b0 = (cfp)d_in[11];
  cfp g0_w1 = (cfp)d_in[12], g0_b1 = (cfp)d_in[13];
  cfp g1_w0 = (cfp)d_in[14], g1_b0 = (cfp)d_in[15];
  cfp g1_w1 = (cfp)d_in[16], g1_b1 = (cfp)d_in[17];
  cfp v_w0  = (cfp)d_in[18], v_b0  = (cfp)d_in[19];
  cfp v_w1  = (cfp)d_in[20], v_b1  = (cfp)d_in[21];
  cfp v_w2  = (cfp)d_in[22], v_b2  = (cfp)d_in[23];
  float* out = (float*)d_out;

  const int B = in_sizes[0] / 750;
  hipLaunchKernelGGL(value_net_kernel, dim3(B), dim3(256), 0, stream,
                     state,
                     wr_w0, wr_b0, wr_w1, wr_b1,
                     wh_w0, wh_b0, wh_w1, wh_b1,
                     g0_w0, g0_b0, g0_w1, g0_b1,
                     g1_w0, g1_b0, g1_w1, g1_b1,
                     v_w0, v_b0, v_w1, v_b1, v_w2, v_b2,
                     out);
}

// Round 4
// 137.332 us; speedup vs baseline: 1.3256x; 1.0376x over previous
//
#include <hip/hip_runtime.h>
#include <hip/hip_bf16.h>

// Fused GAT value network, one block per batch element. FLOAT32 in/out.
// Rank-split GAT1 scores, row-0-only GAT2, all intermediates in LDS.
// R4: packed-f32 vector math (v_pk_fma_f32), f4-vectorized attention reads
// (sE stride 52), GAT2 weight staging overlapped with E (F1 barrier removed),
// 4-row E tile. 12 barriers.

typedef float f4 __attribute__((ext_vector_type(4)));
typedef const float* cfp;

__device__ __forceinline__ f4 fma4(float s, f4 v, f4 a) { return a + s * v; }
__device__ __forceinline__ f4 max4(f4 a, f4 b) {
  f4 r;
#pragma unroll
  for (int i = 0; i < 4; ++i) r[i] = fmaxf(a[i], b[i]);
  return r;
}

#define NN 51
#define HID 64
#define XD 32
#define XS 9   // row stride of X/H1 in f4 (36 floats) — breaks 4-way bank conflicts
#define ES 52  // row stride of attention matrix in floats (13 f4, padded col)

__global__ __launch_bounds__(256)
void value_net_kernel(cfp state,
                      cfp wr_w0, cfp wr_b0, cfp wr_w1, cfp wr_b1,
                      cfp wh_w0, cfp wh_b0, cfp wh_w1, cfp wh_b1,
                      cfp g0_w0, cfp g0_b0, cfp g0_w1, cfp g0_b1,
                      cfp g1_w0, cfp g1_b0, cfp g1_w1, cfp g1_b1,
                      cfp v_w0, cfp v_b0, cfp v_w1, cfp v_b1,
                      cfp v_w2, cfp v_b2,
                      float* out)
{
  // Row 51 everywhere is read-safe scratch for the register-tiled loops.
  __shared__ f4 sX4[52 * XS];   // X
  __shared__ f4 sH14[52 * XS];  // H1
  __shared__ f4 sU4[52 * 17];   // U(+b0) stride 68f (also: sHH scratch; W0b stage + U2)
  __shared__ f4 sV4[52 * 17];   // V (also: staged wh_w1; V2)
  __shared__ f4 sWE4[1024];     // staged W0 (4096f) (also: att matrix stride 52 + head partials)
  __shared__ f4 sB04[16];
  __shared__ f4 sW14[16];
  __shared__ float sRH[64];
  __shared__ float sO[32];
  __shared__ float sM1[152];
  __shared__ float sM2[104];

  float* sX  = (float*)sX4;
  float* sH1 = (float*)sH14;
  float* sE  = (float*)sWE4;   // att scores alias (disjoint live range vs W0)
  float* sHH = (float*)sU4;    // human-hidden scratch, row stride 68
  const f4* sWh4 = (const f4*)sV4;

  const int tid = threadIdx.x;
  const int b = blockIdx.x;
  cfp st = state + b * 750;

  const float gb0 = g0_b1[0];
  const float gb1 = g1_b1[0];

  // ---- A1: stage weights; robot/human hidden layers
  {
    const f4* g0w04 = (const f4*)g0_w0;
    for (int i = tid; i < 1024; i += 256) sWE4[i] = g0w04[i];
    const f4* whw14 = (const f4*)wh_w1;
    f4* sWh4w = (f4*)sV4;
    for (int i = tid; i < 512; i += 256) sWh4w[i] = whw14[i];
  }
  if (tid < HID) {
    ((float*)sB04)[tid] = g0_b0[tid];
    ((float*)sW14)[tid] = g0_w1[tid];
    float a = wr_b0[tid];
#pragma unroll
    for (int k = 0; k < 9; ++k) a = fmaf(st[k], wr_w0[k * HID + tid], a);
    sRH[tid] = fmaxf(a, 0.f);
  }
  if (tid < XS) { sX4[51 * XS + tid] = (f4){0,0,0,0}; sH14[51 * XS + tid] = (f4){0,0,0,0}; }
  for (int idx = tid; idx < 50 * HID; idx += 256) {
    int i = idx >> 6, t = idx & 63;
    cfp hp = st + i * 15 + 9;
    float a = wh_b0[t];
#pragma unroll
    for (int k = 0; k < 6; ++k) a = fmaf(hp[k], wh_w0[k * HID + t], a);
    sHH[i * 68 + t] = fmaxf(a, 0.f);
  }
  __syncthreads();

  // ---- A2: embeddings -> sX (row 0 robot, rows 1..50 humans), 2-row tile
  if (tid < XD) {
    float a = wr_b1[tid];
#pragma unroll 8
    for (int t = 0; t < HID; ++t) a = fmaf(sRH[t], wr_w1[t * XD + tid], a);
    sX[tid] = fmaxf(a, 0.f);
  }
  if (tid < 200) {
    int ip = tid >> 3, fg = tid & 7;           // rows ip+1, ip+26
    f4 a0 = { wh_b1[fg * 4 + 0], wh_b1[fg * 4 + 1],
              wh_b1[fg * 4 + 2], wh_b1[fg * 4 + 3] };
    f4 a1 = a0;
    const f4* h0 = sU4 + ip * 17;
    const f4* h1 = sU4 + (ip + 25) * 17;
#pragma unroll 4
    for (int tg = 0; tg < 16; ++tg) {
      f4 ha = h0[tg], hb = h1[tg];
#pragma unroll
      for (int e = 0; e < 4; ++e) {
        f4 w = sWh4[(tg * 4 + e) * 8 + fg];
        a0 = fma4(ha[e], w, a0);
        a1 = fma4(hb[e], w, a1);
      }
    }
    f4 z = {0,0,0,0};
    sX4[(1 + ip) * XS + fg] = max4(a0, z);
    sX4[(26 + ip) * XS + fg] = max4(a1, z);
  }
  __syncthreads();

  // ---- B: U = X@W0a + b0 ; V = X@W0b  — 4-row tile, 208 tasks
  if (tid < 208) {
    int ip = tid >> 4, tg = tid & 15;          // rows ip+13r (row 51 = scratch, zero)
    f4 au[4] = {{0,0,0,0},{0,0,0,0},{0,0,0,0},{0,0,0,0}};
    f4 av[4] = {{0,0,0,0},{0,0,0,0},{0,0,0,0},{0,0,0,0}};
#pragma unroll 2
    for (int kg = 0; kg < 8; ++kg) {
      f4 x0 = sX4[ip * XS + kg];
      f4 x1 = sX4[(ip + 13) * XS + kg];
      f4 x2 = sX4[(ip + 26) * XS + kg];
      f4 x3 = sX4[(ip + 39) * XS + kg];
#pragma unroll
      for (int e = 0; e < 4; ++e) {
        int k = kg * 4 + e;
        f4 wU = sWE4[k * 16 + tg];
        f4 wV = sWE4[(k + 32) * 16 + tg];
        au[0] = fma4(x0[e], wU, au[0]); av[0] = fma4(x0[e], wV, av[0]);
        au[1] = fma4(x1[e], wU, au[1]); av[1] = fma4(x1[e], wV, av[1]);
        au[2] = fma4(x2[e], wU, au[2]); av[2] = fma4(x2[e], wV, av[2]);
        au[3] = fma4(x3[e], wU, au[3]); av[3] = fma4(x3[e], wV, av[3]);
      }
    }
    f4 b0v = sB04[tg];
#pragma unroll
    for (int r = 0; r < 4; ++r) {
      int row = ip + 13 * r;
      sU4[row * 17 + tg] = au[r] + b0v;
      sV4[row * 17 + tg] = av[r];
    }
  }
  __syncthreads();

  // ---- C: pairwise scores, 4x4 tile, packed-f32 vector accumulation
  if (tid < 169) {
    int it = tid / 13, jt = tid - (tid / 13) * 13;
    const f4* U0 = sU4 + it * 17;
    const f4* V0 = sV4 + jt * 17;
    f4 acc[4][4] = {};
    const f4 z = {0,0,0,0};
#pragma unroll 2
    for (int g = 0; g < 16; ++g) {
      f4 uu[4] = {U0[g], U0[221 + g], U0[442 + g], U0[663 + g]};  // 13*17=221
      f4 vv[4] = {V0[g], V0[221 + g], V0[442 + g], V0[663 + g]};
      f4 w = sW14[g];
#pragma unroll
      for (int r = 0; r < 4; ++r)
#pragma unroll
        for (int cc = 0; cc < 4; ++cc)
          acc[r][cc] += max4(uu[r] + vv[cc], z) * w;   // pk_add/pk_max/pk_fma
    }
#pragma unroll
    for (int r = 0; r < 4; ++r) {
      int i = it + 13 * r;
      if (i < NN) {
#pragma unroll
        for (int cc = 0; cc < 4; ++cc) {
          int j = jt + 13 * cc;
          if (j < NN) {
            f4 A4 = acc[r][cc];
            float A = (A4[0] + A4[1]) + (A4[2] + A4[3]) + gb0;
            float e = A > 0.f ? A : 0.04f * A;
            sE[i * ES + j] = (j == 0 && i > 0) ? -1e30f : e;
          }
        }
      }
    }
  }
  __syncthreads();

  // ---- D: row softmax — lane-parallel rows across all 4 waves
  {
    int lane = tid & 63, w = tid >> 6;
    for (int r = w; r < NN; r += 4) {
      float* row = sE + r * ES;
      float e = (lane < NN) ? row[lane] : -3.0e38f;
      float m = e;
#pragma unroll
      for (int o = 32; o; o >>= 1) m = fmaxf(m, __shfl_xor(m, o, 64));
      float p = (lane < NN) ? __expf(e - m) : 0.f;
      float s = p;
#pragma unroll
      for (int o = 32; o; o >>= 1) s += __shfl_xor(s, o, 64);
      if (lane < NN) row[lane] = p / s;       // col0 (r>0): exp(-1e30-m)=0
      else if (lane == NN) row[lane] = 0.f;   // padding col for f4 reads
    }
  }
  __syncthreads();

  // ---- E: H1 = att @ X — 4-row tile (104 threads); threads 104+ stage GAT2 weights
  if (tid < 104) {
    int ip = tid >> 3, q = tid & 7;            // 13 row-tiles x 8 col-f4
    const f4* a0 = (const f4*)(sE + ip * ES);
    const f4* a1 = (const f4*)(sE + (ip + 13) * ES);
    const f4* a2 = (const f4*)(sE + (ip + 26) * ES);
    const f4* a3 = (const f4*)(sE + (ip + 39) * ES);  // row 51: garbage att x zero X
    f4 b0 = {0,0,0,0}, b1 = {0,0,0,0}, b2 = {0,0,0,0}, b3 = {0,0,0,0};
    for (int jg = 0; jg < 13; ++jg) {
      f4 t0 = a0[jg], t1 = a1[jg], t2 = a2[jg], t3 = a3[jg];
#pragma unroll
      for (int e = 0; e < 4; ++e) {
        f4 x = sX4[(jg * 4 + e) * XS + q];     // row 51 is zero
        b0 = fma4(t0[e], x, b0);
        b1 = fma4(t1[e], x, b1);
        b2 = fma4(t2[e], x, b2);
        b3 = fma4(t3[e], x, b3);
      }
    }
    sH14[ip * XS + q] = b0;
    sH14[(ip + 13) * XS + q] = b1;
    sH14[(ip + 26) * XS + q] = b2;
    sH14[(ip + 39) * XS + q] = b3;
  } else if (tid < 232) {
    // stage g1_w0 rows 32..63 (W0b, 512 f4) into sU4[0..512) — sU dead after C
    int t = tid - 104;                         // 0..127
    const f4* g1w = (const f4*)g1_w0;
#pragma unroll
    for (int i = 0; i < 4; ++i) sU4[t + 128 * i] = g1w[512 + t + 128 * i];
  } else if (tid < 248) {
    sB04[tid - 232] = ((const f4*)g1_b0)[tid - 232];
  } else {
    int t = tid - 248;
    sW14[t] = ((const f4*)g1_w1)[t];
    sW14[t + 8] = ((const f4*)g1_w1)[t + 8];
  }
  __syncthreads();

  // ---- F2: V2 = H1@W0b (4-row tile, W0b from sU4); U2 = H1[0]@W0a + b0 (from global)
  if (tid < 208) {
    int jp = tid >> 4, tg = tid & 15;
    f4 av[4] = {{0,0,0,0},{0,0,0,0},{0,0,0,0},{0,0,0,0}};
#pragma unroll 2
    for (int kg = 0; kg < 8; ++kg) {
      f4 h0 = sH14[jp * XS + kg];
      f4 h1 = sH14[(jp + 13) * XS + kg];
      f4 h2 = sH14[(jp + 26) * XS + kg];
      f4 h3 = sH14[(jp + 39) * XS + kg];
#pragma unroll
      for (int e = 0; e < 4; ++e) {
        f4 wV = sU4[(kg * 4 + e) * 16 + tg];
        av[0] = fma4(h0[e], wV, av[0]);
        av[1] = fma4(h1[e], wV, av[1]);
        av[2] = fma4(h2[e], wV, av[2]);
        av[3] = fma4(h3[e], wV, av[3]);
      }
    }
#pragma unroll
    for (int r = 0; r < 4; ++r) sV4[(jp + 13 * r) * 17 + tg] = av[r];
  } else if (tid < 224) {
    int tg = tid - 208;
    const f4* w0g = (const f4*)g1_w0;          // W0a rows 0..31 straight from global
    f4 au = {0,0,0,0};
#pragma unroll 2
    for (int kg = 0; kg < 8; ++kg) {
      f4 h = sH14[kg];
#pragma unroll
      for (int e = 0; e < 4; ++e) au = fma4(h[e], w0g[(kg * 4 + e) * 16 + tg], au);
    }
    sU4[512 + tg] = au + sB04[tg];
  }
  __syncthreads();

  // ---- G: GAT2 row-0 scores + softmax (wave 0) -> sE[0..50]
  if (tid < 64) {
    int j = tid;
    float e = -3.0e38f;
    if (j < NN) {
      f4 acc4 = {0,0,0,0};
#pragma unroll 4
      for (int g = 0; g < 16; ++g) {
        f4 u = sU4[512 + g];
        f4 v = sV4[j * 17 + g];
        f4 w = sW14[g];
        f4 z = {0,0,0,0};
        acc4 += max4(u + v, z) * w;
      }
      float acc = (acc4[0] + acc4[1]) + (acc4[2] + acc4[3]) + gb1;
      e = acc > 0.f ? acc : 0.04f * acc;
    }
    float m = e;
#pragma unroll
    for (int o = 32; o; o >>= 1) m = fmaxf(m, __shfl_xor(m, o, 64));
    float p = (j < NN) ? __expf(e - m) : 0.f;
    float s = p;
#pragma unroll
    for (int o = 32; o; o >>= 1) s += __shfl_xor(s, o, 64);
    if (j < NN) sE[j] = p / s;
  }
  __syncthreads();

  // ---- H: row 0 of (H1 + H2 + X)
  if (tid < XD) {
    float a = 0.f;
    for (int j = 0; j < NN; ++j) a = fmaf(sE[j], sH1[j * 36 + tid], a);
    sO[tid] = a + sH1[tid] + sX[tid];
  }
  __syncthreads();

  // ---- I: value head 32 -> 150 -> 100 -> 1
  if (tid < 150) {
    float a = v_b0[tid];
#pragma unroll 8
    for (int k = 0; k < 32; ++k) a = fmaf(sO[k], v_w0[k * 150 + tid], a);
    sM1[tid] = fmaxf(a, 0.f);
  }
  __syncthreads();
  if (tid < 250) {
    int kp = tid / 50, t2 = tid % 50;
    const float2* w = (const float2*)v_w1;
    float2 acc = {0.f, 0.f};
    for (int k = kp * 30; k < kp * 30 + 30; ++k) {
      float2 ww = w[k * 50 + t2];
      float xv = sM1[k];
      acc.x = fmaf(xv, ww.x, acc.x);
      acc.y = fmaf(xv, ww.y, acc.y);
    }
    ((float2*)(sE + 768 + kp * 100))[t2] = acc;
  }
  __syncthreads();
  if (tid < 100) {
    float a = v_b1[tid];
#pragma unroll
    for (int kp = 0; kp < 5; ++kp) a += sE[768 + kp * 100 + tid];
    sM2[tid] = fmaxf(a, 0.f);
  }
  __syncthreads();
  if (tid < 64) {
    float a = sM2[tid] * v_w2[tid];
    if (tid < 36) a = fmaf(sM2[tid + 64], v_w2[tid + 64], a);
#pragma unroll
    for (int o = 32; o; o >>= 1) a += __shfl_xor(a, o, 64);
    if (tid == 0) out[b] = fmaxf(a + v_b2[0], 0.f);
  }
}

extern "C" void kernel_launch(void* const* d_in, const int* in_sizes, int n_in,
                              void* d_out, int out_size, void* d_ws, size_t ws_size,
                              hipStream_t stream) {
  cfp state = (cfp)d_in[0];
  cfp wr_w0 = (cfp)d_in[2],  cfp_wr_b0 = (cfp)d_in[3];
  cfp wr_w1 = (cfp)d_in[4],  wr_b1 = (cfp)d_in[5];
  cfp wh_w0 = (cfp)d_in[6],  wh_b0 = (cfp)d_in[7];
  cfp wh_w1 = (cfp)d_in[8],  wh_b1 = (cfp)d_in[9];
  cfp g0_w0 = (cfp)d_in[10], g0_b0 = (cfp)d_in[11];
  cfp g0_w1 = (cfp)d_in[12], g0_b1 = (cfp)d_in[13];
  cfp g1_w0 = (cfp)d_in[14], g1_b0 = (cfp)d_in[15];
  cfp g1_w1 = (cfp)d_in[16], g1_b1 = (cfp)d_in[17];
  cfp v_w0  = (cfp)d_in[18], v_b0  = (cfp)d_in[19];
  cfp v_w1  = (cfp)d_in[20], v_b1  = (cfp)d_in[21];
  cfp v_w2  = (cfp)d_in[22], v_b2  = (cfp)d_in[23];
  float* out = (float*)d_out;

  const int B = in_sizes[0] / 750;
  hipLaunchKernelGGL(value_net_kernel, dim3(B), dim3(256), 0, stream,
                     state,
                     wr_w0, cfp_wr_b0, wr_w1, wr_b1,
                     wh_w0, wh_b0, wh_w1, wh_b1,
                     g0_w0, g0_b0, g0_w1, g0_b1,
                     g1_w0, g1_b0, g1_w1, g1_b1,
                     v_w0, v_b0, v_w1, v_b1, v_w2, v_b2,
                     out);
}

// Round 5
// 130.569 us; speedup vs baseline: 1.3943x; 1.0518x over previous
//
#include <hip/hip_runtime.h>
#include <hip/hip_bf16.h>

// Fused GAT value network, one block per batch element. FLOAT32 in/out.
// Rank-split GAT1 scores, row-0-only GAT2, all intermediates in LDS.
// R5: 512-thread blocks (same 62KB LDS -> 2 blocks/CU -> 16 waves/CU vs 8).
// Heavy phases re-tiled to >256 tasks: B/F2 3-row tiles (272), C 3x3 (289),
// softmax over 8 waves, I2 10-way k-split. E keeps 2-row + overlapped staging.

typedef float f4 __attribute__((ext_vector_type(4)));
typedef const float* cfp;

__device__ __forceinline__ f4 fma4(float s, f4 v, f4 a) { return a + s * v; }
__device__ __forceinline__ f4 max4(f4 a, f4 b) {
  f4 r;
#pragma unroll
  for (int i = 0; i < 4; ++i) r[i] = fmaxf(a[i], b[i]);
  return r;
}

#define NN 51
#define HID 64
#define XD 32
#define XS 9   // row stride of X/H1 in f4 (36 floats) — breaks 4-way bank conflicts
#define ES 52  // row stride of attention matrix in floats (13 f4, padded col)

__global__ __launch_bounds__(512, 4)
void value_net_kernel(cfp state,
                      cfp wr_w0, cfp wr_b0, cfp wr_w1, cfp wr_b1,
                      cfp wh_w0, cfp wh_b0, cfp wh_w1, cfp wh_b1,
                      cfp g0_w0, cfp g0_b0, cfp g0_w1, cfp g0_b1,
                      cfp g1_w0, cfp g1_b0, cfp g1_w1, cfp g1_b1,
                      cfp v_w0, cfp v_b0, cfp v_w1, cfp v_b1,
                      cfp v_w2, cfp v_b2,
                      float* out)
{
  __shared__ f4 sX4[52 * XS];   // X (row 51 = zero scratch)
  __shared__ f4 sH14[52 * XS];  // H1
  __shared__ f4 sU4[52 * 17];   // U(+b0) stride 68f (also: sHH scratch; W0b stage + U2)
  __shared__ f4 sV4[52 * 17];   // V (also: staged wh_w1; V2)
  __shared__ f4 sWE4[1024];     // staged W0 (4096f) (also: att matrix stride 52 + head partials)
  __shared__ f4 sB04[16];
  __shared__ f4 sW14[16];
  __shared__ float sRH[64];
  __shared__ float sO[32];
  __shared__ float sM1[152];
  __shared__ float sM2[104];

  float* sX  = (float*)sX4;
  float* sH1 = (float*)sH14;
  float* sE  = (float*)sWE4;   // att scores alias (disjoint live range vs W0)
  float* sHH = (float*)sU4;    // human-hidden scratch, row stride 68
  const f4* sWh4 = (const f4*)sV4;

  const int tid = threadIdx.x;
  const int b = blockIdx.x;
  cfp st = state + b * 750;

  const float gb0 = g0_b1[0];
  const float gb1 = g1_b1[0];

  // ---- A1: stage weights; robot/human hidden layers
  {
    const f4* g0w04 = (const f4*)g0_w0;
    for (int i = tid; i < 1024; i += 512) sWE4[i] = g0w04[i];
    const f4* whw14 = (const f4*)wh_w1;
    f4* sWh4w = (f4*)sV4;
    if (tid < 512) sWh4w[tid] = whw14[tid];
  }
  if (tid < HID) {
    ((float*)sB04)[tid] = g0_b0[tid];
    ((float*)sW14)[tid] = g0_w1[tid];
    float a = wr_b0[tid];
#pragma unroll
    for (int k = 0; k < 9; ++k) a = fmaf(st[k], wr_w0[k * HID + tid], a);
    sRH[tid] = fmaxf(a, 0.f);
  }
  if (tid >= 64 && tid < 64 + XS) sX4[51 * XS + (tid - 64)] = (f4){0,0,0,0};
  for (int idx = tid; idx < 50 * HID; idx += 512) {
    int i = idx >> 6, t = idx & 63;
    cfp hp = st + i * 15 + 9;
    float a = wh_b0[t];
#pragma unroll
    for (int k = 0; k < 6; ++k) a = fmaf(hp[k], wh_w0[k * HID + t], a);
    sHH[i * 68 + t] = fmaxf(a, 0.f);
  }
  __syncthreads();

  // ---- A2: embeddings -> sX (row 0 robot, rows 1..50 humans), 2-row tile
  if (tid < 200) {
    int ip = tid >> 3, fg = tid & 7;           // rows ip+1, ip+26
    f4 a0 = { wh_b1[fg * 4 + 0], wh_b1[fg * 4 + 1],
              wh_b1[fg * 4 + 2], wh_b1[fg * 4 + 3] };
    f4 a1 = a0;
    const f4* h0 = sU4 + ip * 17;
    const f4* h1 = sU4 + (ip + 25) * 17;
#pragma unroll 4
    for (int tg = 0; tg < 16; ++tg) {
      f4 ha = h0[tg], hb = h1[tg];
#pragma unroll
      for (int e = 0; e < 4; ++e) {
        f4 w = sWh4[(tg * 4 + e) * 8 + fg];
        a0 = fma4(ha[e], w, a0);
        a1 = fma4(hb[e], w, a1);
      }
    }
    f4 z = {0,0,0,0};
    sX4[(1 + ip) * XS + fg] = max4(a0, z);
    sX4[(26 + ip) * XS + fg] = max4(a1, z);
  } else if (tid >= 448 && tid < 448 + XD) {
    int t = tid - 448;
    float a = wr_b1[t];
#pragma unroll 8
    for (int k = 0; k < HID; ++k) a = fmaf(sRH[k], wr_w1[k * XD + t], a);
    sX[t] = fmaxf(a, 0.f);
  }
  __syncthreads();

  // ---- B: U = X@W0a + b0 ; V = X@W0b  — 3-row tile, 272 tasks (rows i+17r: 0..50)
  if (tid < 272) {
    int ip = tid >> 4, tg = tid & 15;
    f4 au[3] = {{0,0,0,0},{0,0,0,0},{0,0,0,0}};
    f4 av[3] = {{0,0,0,0},{0,0,0,0},{0,0,0,0}};
#pragma unroll 2
    for (int kg = 0; kg < 8; ++kg) {
      f4 x0 = sX4[ip * XS + kg];
      f4 x1 = sX4[(ip + 17) * XS + kg];
      f4 x2 = sX4[(ip + 34) * XS + kg];
#pragma unroll
      for (int e = 0; e < 4; ++e) {
        int k = kg * 4 + e;
        f4 wU = sWE4[k * 16 + tg];
        f4 wV = sWE4[(k + 32) * 16 + tg];
        au[0] = fma4(x0[e], wU, au[0]); av[0] = fma4(x0[e], wV, av[0]);
        au[1] = fma4(x1[e], wU, au[1]); av[1] = fma4(x1[e], wV, av[1]);
        au[2] = fma4(x2[e], wU, au[2]); av[2] = fma4(x2[e], wV, av[2]);
      }
    }
    f4 b0v = sB04[tg];
#pragma unroll
    for (int r = 0; r < 3; ++r) {
      int row = ip + 17 * r;
      sU4[row * 17 + tg] = au[r] + b0v;
      sV4[row * 17 + tg] = av[r];
    }
  }
  __syncthreads();

  // ---- C: pairwise scores, 3x3 tile, 289 tasks, packed-f32 accumulation
  if (tid < 289) {
    int it = tid / 17, jt = tid - (tid / 17) * 17;
    const f4* U0 = sU4 + it * 17;
    const f4* V0 = sV4 + jt * 17;
    f4 acc[3][3] = {};
    const f4 z = {0,0,0,0};
#pragma unroll 4
    for (int g = 0; g < 16; ++g) {
      f4 uu[3] = {U0[g], U0[289 + g], U0[578 + g]};   // 17*17=289 f4 row offset
      f4 vv[3] = {V0[g], V0[289 + g], V0[578 + g]};
      f4 w = sW14[g];
#pragma unroll
      for (int r = 0; r < 3; ++r)
#pragma unroll
        for (int cc = 0; cc < 3; ++cc)
          acc[r][cc] += max4(uu[r] + vv[cc], z) * w;
    }
#pragma unroll
    for (int r = 0; r < 3; ++r) {
      int i = it + 17 * r;
#pragma unroll
      for (int cc = 0; cc < 3; ++cc) {
        int j = jt + 17 * cc;
        f4 A4 = acc[r][cc];
        float A = (A4[0] + A4[1]) + (A4[2] + A4[3]) + gb0;
        float e = A > 0.f ? A : 0.04f * A;
        sE[i * ES + j] = (j == 0 && i > 0) ? -1e30f : e;
      }
    }
  }
  __syncthreads();

  // ---- D: row softmax — lane-parallel rows across all 8 waves
  {
    int lane = tid & 63, w = tid >> 6;
    for (int r = w; r < NN; r += 8) {
      float* row = sE + r * ES;
      float e = (lane < NN) ? row[lane] : -3.0e38f;
      float m = e;
#pragma unroll
      for (int o = 32; o; o >>= 1) m = fmaxf(m, __shfl_xor(m, o, 64));
      float p = (lane < NN) ? __expf(e - m) : 0.f;
      float s = p;
#pragma unroll
      for (int o = 32; o; o >>= 1) s += __shfl_xor(s, o, 64);
      if (lane < NN) row[lane] = p / s;       // col0 (r>0): exp(-1e30-m)=0
      else if (lane == NN) row[lane] = 0.f;   // padding col for f4 reads
    }
  }
  __syncthreads();

  // ---- E: H1 = att @ X — 2-row tile (208 threads); threads 352+ stage GAT2 weights
  if (tid < 208) {
    int ip = tid >> 3, q = tid & 7;            // rows ip, ip+26 (26 tiles x 8 col-f4)
    const f4* a0 = (const f4*)(sE + ip * ES);
    const f4* a1 = (const f4*)(sE + (ip + 26) * ES);  // row 51: finite garbage, harmless
    f4 b0 = {0,0,0,0}, b1 = {0,0,0,0};
    for (int jg = 0; jg < 13; ++jg) {
      f4 t0 = a0[jg], t1 = a1[jg];
#pragma unroll
      for (int e = 0; e < 4; ++e) {
        f4 x = sX4[(jg * 4 + e) * XS + q];     // row 51 is zero; att col 51 is zero
        b0 = fma4(t0[e], x, b0);
        b1 = fma4(t1[e], x, b1);
      }
    }
    sH14[ip * XS + q] = b0;
    sH14[(ip + 26) * XS + q] = b1;
  } else if (tid >= 384) {
    // stage g1_w0 rows 32..63 (W0b, 512 f4) into sU4[0..512) — sU dead after C
    int t = tid - 384;                         // 0..127
    const f4* g1w = (const f4*)g1_w0;
#pragma unroll
    for (int i = 0; i < 4; ++i) sU4[t + 128 * i] = g1w[512 + t + 128 * i];
  } else if (tid >= 352 && tid < 368) {
    sB04[tid - 352] = ((const f4*)g1_b0)[tid - 352];
  } else if (tid >= 368 && tid < 384) {
    sW14[tid - 368] = ((const f4*)g1_w1)[tid - 368];
  }
  __syncthreads();

  // ---- F2: V2 = H1@W0b (3-row tile, 272 tasks); U2 = H1[0]@W0a + b0 (from global)
  if (tid < 272) {
    int jp = tid >> 4, tg = tid & 15;          // rows jp+17r: 0..50
    f4 av[3] = {{0,0,0,0},{0,0,0,0},{0,0,0,0}};
#pragma unroll 2
    for (int kg = 0; kg < 8; ++kg) {
      f4 h0 = sH14[jp * XS + kg];
      f4 h1 = sH14[(jp + 17) * XS + kg];
      f4 h2 = sH14[(jp + 34) * XS + kg];
#pragma unroll
      for (int e = 0; e < 4; ++e) {
        f4 wV = sU4[(kg * 4 + e) * 16 + tg];
        av[0] = fma4(h0[e], wV, av[0]);
        av[1] = fma4(h1[e], wV, av[1]);
        av[2] = fma4(h2[e], wV, av[2]);
      }
    }
#pragma unroll
    for (int r = 0; r < 3; ++r) sV4[(jp + 17 * r) * 17 + tg] = av[r];
  } else if (tid < 288) {
    int tg = tid - 272;
    const f4* w0g = (const f4*)g1_w0;          // W0a rows 0..31 straight from global
    f4 au = {0,0,0,0};
#pragma unroll 2
    for (int kg = 0; kg < 8; ++kg) {
      f4 h = sH14[kg];
#pragma unroll
      for (int e = 0; e < 4; ++e) au = fma4(h[e], w0g[(kg * 4 + e) * 16 + tg], au);
    }
    sU4[512 + tg] = au + sB04[tg];
  }
  __syncthreads();

  // ---- G: GAT2 row-0 scores + softmax (wave 0) -> sE[0..50]
  if (tid < 64) {
    int j = tid;
    float e = -3.0e38f;
    if (j < NN) {
      f4 acc4 = {0,0,0,0};
#pragma unroll 4
      for (int g = 0; g < 16; ++g) {
        f4 u = sU4[512 + g];
        f4 v = sV4[j * 17 + g];
        f4 w = sW14[g];
        f4 z = {0,0,0,0};
        acc4 += max4(u + v, z) * w;
      }
      float acc = (acc4[0] + acc4[1]) + (acc4[2] + acc4[3]) + gb1;
      e = acc > 0.f ? acc : 0.04f * acc;
    }
    float m = e;
#pragma unroll
    for (int o = 32; o; o >>= 1) m = fmaxf(m, __shfl_xor(m, o, 64));
    float p = (j < NN) ? __expf(e - m) : 0.f;
    float s = p;
#pragma unroll
    for (int o = 32; o; o >>= 1) s += __shfl_xor(s, o, 64);
    if (j < NN) sE[j] = p / s;
  }
  __syncthreads();

  // ---- H: row 0 of (H1 + H2 + X)
  if (tid < XD) {
    float a = 0.f;
    for (int j = 0; j < NN; ++j) a = fmaf(sE[j], sH1[j * 36 + tid], a);
    sO[tid] = a + sH1[tid] + sX[tid];
  }
  __syncthreads();

  // ---- I: value head 32 -> 150 -> 100 -> 1
  if (tid < 150) {
    float a = v_b0[tid];
#pragma unroll 8
    for (int k = 0; k < 32; ++k) a = fmaf(sO[k], v_w0[k * 150 + tid], a);
    sM1[tid] = fmaxf(a, 0.f);
  }
  __syncthreads();
  if (tid < 500) {
    int kp = tid / 50, t2 = tid % 50;          // 10-way k-split
    const float2* w = (const float2*)v_w1;
    float2 acc = {0.f, 0.f};
    for (int k = kp * 15; k < kp * 15 + 15; ++k) {
      float2 ww = w[k * 50 + t2];
      float xv = sM1[k];
      acc.x = fmaf(xv, ww.x, acc.x);
      acc.y = fmaf(xv, ww.y, acc.y);
    }
    ((float2*)(sE + 768 + kp * 100))[t2] = acc;
  }
  __syncthreads();
  if (tid < 100) {
    float a = v_b1[tid];
#pragma unroll
    for (int kp = 0; kp < 10; ++kp) a += sE[768 + kp * 100 + tid];
    sM2[tid] = fmaxf(a, 0.f);
  }
  __syncthreads();
  if (tid < 64) {
    float a = sM2[tid] * v_w2[tid];
    if (tid < 36) a = fmaf(sM2[tid + 64], v_w2[tid + 64], a);
#pragma unroll
    for (int o = 32; o; o >>= 1) a += __shfl_xor(a, o, 64);
    if (tid == 0) out[b] = fmaxf(a + v_b2[0], 0.f);
  }
}

extern "C" void kernel_launch(void* const* d_in, const int* in_sizes, int n_in,
                              void* d_out, int out_size, void* d_ws, size_t ws_size,
                              hipStream_t stream) {
  cfp state = (cfp)d_in[0];
  cfp wr_w0 = (cfp)d_in[2],  wr_b0 = (cfp)d_in[3];
  cfp wr_w1 = (cfp)d_in[4],  wr_b1 = (cfp)d_in[5];
  cfp wh_w0 = (cfp)d_in[6],  wh_b0 = (cfp)d_in[7];
  cfp wh_w1 = (cfp)d_in[8],  wh_b1 = (cfp)d_in[9];
  cfp g0_w0 = (cfp)d_in[10], g0_b0 = (cfp)d_in[11];
  cfp g0_w1 = (cfp)d_in[12], g0_b1 = (cfp)d_in[13];
  cfp g1_w0 = (cfp)d_in[14], g1_b0 = (cfp)d_in[15];
  cfp g1_w1 = (cfp)d_in[16], g1_b1 = (cfp)d_in[17];
  cfp v_w0  = (cfp)d_in[18], v_b0  = (cfp)d_in[19];
  cfp v_w1  = (cfp)d_in[20], v_b1  = (cfp)d_in[21];
  cfp v_w2  = (cfp)d_in[22], v_b2  = (cfp)d_in[23];
  float* out = (float*)d_out;

  const int B = in_sizes[0] / 750;
  hipLaunchKernelGGL(value_net_kernel, dim3(B), dim3(512), 0, stream,
                     state,
                     wr_w0, wr_b0, wr_w1, wr_b1,
                     wh_w0, wh_b0, wh_w1, wh_b1,
                     g0_w0, g0_b0, g0_w1, g0_b1,
                     g1_w0, g1_b0, g1_w1, g1_b1,
                     v_w0, v_b0, v_w1, v_b1, v_w2, v_b2,
                     out);
}